// Round 11
// baseline (74.905 us; speedup 1.0000x reference)
//
#include <hip/hip_runtime.h>

#define LSEQ 2048
#define DIN  1330
#define NB   8
#define SPLITK 8
#define KCH 168          // k-chunk; s=7 gets 154

__device__ __forceinline__ float lsef(float a, float b) {
  float m = fmaxf(a, b);
  float d = fminf(a, b) - m;
  return m + log1pf(__expf(d));
}

// ---------------- K1: split-k partial GEMM  p[s] = x[:,ks]@w1[ks,:] ----------------
// v8: R=4 rows/thread. r10's version was LDS-pipe-bound: 16 ds_read_b128 per 8-k
// per thread x 8 blocks/CU = 129k LDS cyc/CU = 54 us (measured 60, VALUBusy 17%).
// Sharing each w ds_read across 4 rows cuts LDS instrs 4x -> ~13 us, VALU ~9 us,
// HBM floor ~14 us. Block 256 thr = 256 rows (rslot=tid>>2 owns 4 rows); 512 blocks.
__global__ __launch_bounds__(256) void k1_gemm(
    const float* __restrict__ x, const float* __restrict__ w1,
    float* __restrict__ p) {
  __shared__ float wl[KCH][32];          // 21504 B

  const int tid = threadIdx.x;
  const int rb  = blockIdx.x >> 3;
  const int s   = blockIdx.x & 7;
  const int k0  = s * KCH;
  const int klen = ((k0 + KCH) <= DIN) ? KCH : (DIN - k0);   // 168 or 154

  // ---- stage w slice -> LDS once ----
  for (int it = tid; it < KCH * 8; it += 256) {
    const int i = it >> 3;
    const int j = (it & 7) << 2;
    float4 v = make_float4(0.f, 0.f, 0.f, 0.f);
    if (i < klen) v = *(const float4*)(w1 + (long)(k0 + i) * 32 + j);
    *(float4*)(&wl[i][j]) = v;
  }
  __syncthreads();

  const int hq = tid & 3;
  const int h0 = hq << 3;
  const int rs = tid >> 2;                   // 0..63
  const long row0 = (long)rb * 256 + (long)rs * 4;
  const float* xp = x + row0 * DIN + k0;     // 4 rows: + r*DIN

  float acc[4][8];
  #pragma unroll
  for (int r = 0; r < 4; ++r)
    #pragma unroll
    for (int j = 0; j < 8; ++j) acc[r][j] = 0.f;

  const int klen4 = klen & ~3;               // 168 or 152
  float4 cur[4], nxt[4];
  #pragma unroll
  for (int r = 0; r < 4; ++r) cur[r] = *(const float4*)(xp + r * DIN);

  #pragma unroll 1
  for (int kb = 0; kb < klen4; kb += 4) {
    const int kn = (kb + 4 < klen4) ? (kb + 4) : 0;   // clamp avoids OOB
    #pragma unroll
    for (int r = 0; r < 4; ++r) nxt[r] = *(const float4*)(xp + r * DIN + kn);

    #pragma unroll
    for (int j = 0; j < 4; ++j) {
      const float4 wa = *(const float4*)(&wl[kb + j][h0]);
      const float4 wb = *(const float4*)(&wl[kb + j][h0 + 4]);
      #pragma unroll
      for (int r = 0; r < 4; ++r) {
        const float xs = (j == 0) ? cur[r].x : (j == 1) ? cur[r].y
                       : (j == 2) ? cur[r].z : cur[r].w;
        acc[r][0] += xs * wa.x; acc[r][1] += xs * wa.y;
        acc[r][2] += xs * wa.z; acc[r][3] += xs * wa.w;
        acc[r][4] += xs * wb.x; acc[r][5] += xs * wb.y;
        acc[r][6] += xs * wb.z; acc[r][7] += xs * wb.w;
      }
    }
    #pragma unroll
    for (int r = 0; r < 4; ++r) cur[r] = nxt[r];
  }
  // remainder (s=7: k 152..153)
  for (int k = klen4; k < klen; ++k) {
    const float4 wa = *(const float4*)(&wl[k][h0]);
    const float4 wb = *(const float4*)(&wl[k][h0 + 4]);
    #pragma unroll
    for (int r = 0; r < 4; ++r) {
      const float xs = xp[r * DIN + k];
      acc[r][0] += xs * wa.x; acc[r][1] += xs * wa.y;
      acc[r][2] += xs * wa.z; acc[r][3] += xs * wa.w;
      acc[r][4] += xs * wb.x; acc[r][5] += xs * wb.y;
      acc[r][6] += xs * wb.z; acc[r][7] += xs * wb.w;
    }
  }

  float* ps = p + (long)s * (16384 * 32) + row0 * 32 + h0;
  #pragma unroll
  for (int r = 0; r < 4; ++r) {
    float4 va; va.x = acc[r][0]; va.y = acc[r][1]; va.z = acc[r][2]; va.w = acc[r][3];
    float4 vb; vb.x = acc[r][4]; vb.y = acc[r][5]; vb.z = acc[r][6]; vb.w = acc[r][7];
    *(float4*)(ps + r * 32)     = va;
    *(float4*)(ps + r * 32 + 4) = vb;
  }
}

// ---------------- K2: h = sum_s p[s]+b1 (inline); em = relu(conv1d(h)+cb)@w2+b2 ----
__global__ __launch_bounds__(256) void k2_conv(
    const float* __restrict__ p, const float* __restrict__ b1,
    const float* __restrict__ cw, const float* __restrict__ cb,
    const float* __restrict__ w2, const float* __restrict__ b2,
    float* __restrict__ em) {
  const int g = blockIdx.x * 256 + threadIdx.x;   // 0..131071
  const int row  = g >> 3;
  const int isub = g & 7;
  const int i0   = isub << 2;
  const int li   = row & (LSEQ - 1);

  const float4* p4 = (const float4*)p;
  const float4 bv = ((const float4*)b1)[isub];
  float4 z; z.x = z.y = z.z = z.w = 0.f;

  auto hrow = [&](int r) -> float4 {
    float4 a = p4[(long)r * 8 + isub];
    #pragma unroll
    for (int s = 1; s < SPLITK; ++s) {
      float4 v = p4[(long)s * 131072 + (long)r * 8 + isub];
      a.x += v.x; a.y += v.y; a.z += v.z; a.w += v.w;
    }
    a.x += bv.x; a.y += bv.y; a.z += bv.z; a.w += bv.w;
    return a;
  };

  float4 hm = (li > 0)        ? hrow(row - 1) : z;
  float4 hc = hrow(row);
  float4 hp = (li < LSEQ - 1) ? hrow(row + 1) : z;

  float s[16];
  #pragma unroll
  for (int o = 0; o < 16; ++o) {
    const float4* wpq = (const float4*)(cw + o * 96 + i0 * 3);
    const float4 wa = wpq[0], wb = wpq[1], wc = wpq[2];
    s[o] = hm.x * wa.x + hc.x * wa.y + hp.x * wa.z
         + hm.y * wa.w + hc.y * wb.x + hp.y * wb.y
         + hm.z * wb.z + hc.z * wb.w + hp.z * wc.x
         + hm.w * wc.y + hc.w * wc.z + hp.w * wc.w;
  }
  #pragma unroll
  for (int o = 0; o < 16; ++o) {
    s[o] += __shfl_xor(s[o], 1, 8);
    s[o] += __shfl_xor(s[o], 2, 8);
    s[o] += __shfl_xor(s[o], 4, 8);
  }
  if (isub == 0) {
    float e0 = b2[0], e1 = b2[1];
    #pragma unroll
    for (int o = 0; o < 16; ++o) {
      float rr = fmaxf(s[o] + cb[o], 0.f);
      e0 += rr * w2[o * 2];
      e1 += rr * w2[o * 2 + 1];
    }
    float2 ev; ev.x = e0; ev.y = e1;
    *(float2*)(em + (long)row * 2) = ev;
  }
}

// ---------------- K3: per-batch CRF — fully parallel ----------------
__global__ __launch_bounds__(256) void k3_crf(
    const float* __restrict__ em, const int* __restrict__ tokens_length,
    const int* __restrict__ labels, const float* __restrict__ start_trans,
    const float* __restrict__ end_trans, const float* __restrict__ trans,
    float* __restrict__ llh, float* __restrict__ out) {
  __shared__ float sem[LSEQ * 2];
  __shared__ unsigned char hist[LSEQ];
  __shared__ float4 mats[256];
  __shared__ float red[256];
  __shared__ unsigned char bmA[256], bmB[256];
  __shared__ int s_last;

  const int t = threadIdx.x;
  const int b = blockIdx.x;
  const int len = tokens_length[b];
  const float t00 = trans[0], t01 = trans[1], t10 = trans[2], t11 = trans[3];
  const float st0 = start_trans[0], st1 = start_trans[1];
  const float en0 = end_trans[0], en1 = end_trans[1];
  const int* lab = labels + b * LSEQ;

  {
    const float4* src4 = (const float4*)(em + (long)b * LSEQ * 2);
    float4* dst4 = (float4*)sem;
    #pragma unroll
    for (int i = t; i < LSEQ * 2 / 4; i += 256) dst4[i] = src4[i];
    #pragma unroll
    for (int l = t; l < LSEQ; l += 256) hist[l] = 2;
  }
  __syncthreads();

  int lo = t * 8; if (lo < 1) lo = 1;
  int hi = t * 8 + 8; if (hi > len) hi = len;

  // gold-score partial
  float sc = 0.f;
  {
    const int base = t * 8;
    #pragma unroll
    for (int k = 0; k < 8; ++k) {
      int l = base + k;
      if (l >= 1 && l < len) {
        int lp = lab[l - 1], lc = lab[l];
        sc += trans[lp * 2 + lc] + sem[2 * l + lc];
      }
    }
  }
  red[t] = sc;

  // log-partition chunk product
  {
    float p00 = 0.f, p01 = -1e30f, p10 = -1e30f, p11 = 0.f;
    for (int l = lo; l < hi; ++l) {
      float e0 = sem[2 * l], e1 = sem[2 * l + 1];
      float n00 = lsef(p00 + t00, p01 + t10) + e0;
      float n01 = lsef(p00 + t01, p01 + t11) + e1;
      float n10 = lsef(p10 + t00, p11 + t10) + e0;
      float n11 = lsef(p10 + t01, p11 + t11) + e1;
      p00 = n00; p01 = n01; p10 = n10; p11 = n11;
    }
    float4 m; m.x = p00; m.y = p01; m.z = p10; m.w = p11; mats[t] = m;
  }
  __syncthreads();

  for (int n = 128; n >= 1; n >>= 1) {
    if (t < n) red[t] += red[t + n];
    __syncthreads();
  }
  for (int n = 128; n >= 1; n >>= 1) {
    float4 A, B; const bool act = (t < n);
    if (act) { A = mats[2 * t]; B = mats[2 * t + 1]; }
    __syncthreads();
    if (act) {
      float4 C;
      C.x = lsef(A.x + B.x, A.y + B.z);
      C.y = lsef(A.x + B.y, A.y + B.w);
      C.z = lsef(A.z + B.x, A.w + B.z);
      C.w = lsef(A.z + B.y, A.w + B.w);
      mats[t] = C;
    }
    __syncthreads();
  }

  if (t == 0) {
    int lab0 = lab[0];
    float s0 = (lab0 ? st1 : st0) + sem[lab0];
    int labe = lab[len - 1];
    float score = red[0] + s0 + (labe ? en1 : en0);
    float4 M = mats[0];
    float a00 = st0 + sem[0], a01 = st1 + sem[1];
    float af0 = lsef(a00 + M.x, a01 + M.z);
    float af1 = lsef(a00 + M.y, a01 + M.w);
    float norm = lsef(af0 + en0, af1 + en1);
    llh[b] = score - norm;
  }
  __syncthreads();

  // Viterbi forward: max-plus 2x2 chunk product
  {
    float q00 = 0.f, q01 = -1e30f, q10 = -1e30f, q11 = 0.f;
    for (int l = lo; l < hi; ++l) {
      float e0 = sem[2 * l], e1 = sem[2 * l + 1];
      float n00 = fmaxf(q00 + t00, q01 + t10) + e0;
      float n01 = fmaxf(q00 + t01, q01 + t11) + e1;
      float n10 = fmaxf(q10 + t00, q11 + t10) + e0;
      float n11 = fmaxf(q10 + t01, q11 + t11) + e1;
      q00 = n00; q01 = n01; q10 = n10; q11 = n11;
    }
    float4 m; m.x = q00; m.y = q01; m.z = q10; m.w = q11; mats[t] = m;
  }
  __syncthreads();

  for (int off = 1; off < 256; off <<= 1) {
    float4 cur = mats[t];
    float4 prv;
    const bool has = (t >= off);
    if (has) prv = mats[t - off];
    __syncthreads();
    if (has) {
      float4 c;
      c.x = fmaxf(prv.x + cur.x, prv.y + cur.z);
      c.y = fmaxf(prv.x + cur.y, prv.y + cur.w);
      c.z = fmaxf(prv.z + cur.x, prv.w + cur.z);
      c.w = fmaxf(prv.z + cur.y, prv.w + cur.w);
      mats[t] = c;
    }
    __syncthreads();
  }

  {
    const float v00 = st0 + sem[0], v01 = st1 + sem[1];
    float vp0, vp1;
    if (t == 0) { vp0 = v00; vp1 = v01; }
    else {
      float4 E = mats[t - 1];
      vp0 = fmaxf(v00 + E.x, v01 + E.z);
      vp1 = fmaxf(v00 + E.y, v01 + E.w);
    }
    for (int l = lo; l < hi; ++l) {
      float e0 = sem[2 * l], e1 = sem[2 * l + 1];
      float s00 = vp0 + t00, s10 = vp1 + t10;
      float s01 = vp0 + t01, s11 = vp1 + t11;
      hist[l] = (unsigned char)((s00 >= s10 ? 0 : 1) | ((s01 >= s11 ? 0 : 1) << 1));
      vp0 = fmaxf(s00, s10) + e0;
      vp1 = fmaxf(s01, s11) + e1;
    }
    if (hi == len && lo < hi)
      s_last = (vp0 + en0 >= vp1 + en1) ? 0 : 1;
    if (t == 0 && len == 1)
      s_last = (v00 + en0 >= v01 + en1) ? 0 : 1;
  }
  __syncthreads();
  const int last = s_last;

  // backtrace: parallel map-composition suffix scan
  {
    int blo = (t == 0) ? 1 : t * 8;
    int bhi = t * 8 + 8;
    int m0 = 0, m1 = 1;
    for (int l = bhi - 1; l >= blo; --l) {
      int h = hist[l];
      m0 = (h >> m0) & 1;
      m1 = (h >> m1) & 1;
    }
    bmA[t] = (unsigned char)(m0 | (m1 << 1));
  }
  __syncthreads();
  {
    unsigned char* sarr = bmA; unsigned char* darr = bmB;
    for (int off = 1; off < 256; off <<= 1) {
      int a = sarr[t];
      int c = a;
      if (t + off < 256) {
        int bm = sarr[t + off];
        int c0 = (a >> (bm & 1)) & 1;
        int c1 = (a >> ((bm >> 1) & 1)) & 1;
        c = c0 | (c1 << 1);
      }
      darr[t] = (unsigned char)c;
      __syncthreads();
      unsigned char* tmp = sarr; sarr = darr; darr = tmp;
    }
    int xv = (t == 255) ? last : ((sarr[t + 1] >> last) & 1);
    int blo = (t == 0) ? 1 : t * 8;
    int bhi = t * 8 + 8;
    float* tout = out + 1 + b * LSEQ;
    for (int l = bhi - 1; l >= blo; --l) {
      xv = (hist[l] >> xv) & 1;
      int pidx = l - 1;
      tout[pidx] = (pidx < len) ? (float)xv : 0.0f;
    }
    if (t == 255) tout[LSEQ - 1] = ((LSEQ - 1) < len) ? (float)last : 0.0f;
  }
}

// ---------------- K4: deterministic final sum ----------------
__global__ void k4_final(const float* __restrict__ llh, float* __restrict__ out) {
  if (threadIdx.x == 0 && blockIdx.x == 0) {
    float s = 0.f;
    #pragma unroll
    for (int i = 0; i < NB; ++i) s += llh[i];
    out[0] = -s;
  }
}

extern "C" void kernel_launch(void* const* d_in, const int* in_sizes, int n_in,
                              void* d_out, int out_size, void* d_ws, size_t ws_size,
                              hipStream_t stream) {
  const float* x  = (const float*)d_in[0];
  const int*   tl = (const int*)d_in[1];
  const int*   lb = (const int*)d_in[2];
  const float* w1 = (const float*)d_in[3];
  const float* b1 = (const float*)d_in[4];
  const float* cw = (const float*)d_in[5];
  const float* cb = (const float*)d_in[6];
  const float* w2 = (const float*)d_in[7];
  const float* b2 = (const float*)d_in[8];
  const float* st = (const float*)d_in[9];
  const float* en = (const float*)d_in[10];
  const float* tr = (const float*)d_in[11];
  float* out = (float*)d_out;
  float* ws  = (float*)d_ws;

  float* p   = ws;                                 // 8 * 524288 floats (16 MB)
  float* em  = ws + (long)SPLITK * 524288;         // 32768 floats
  float* llh = em + 32768;                         // 8 floats

  hipLaunchKernelGGL(k1_gemm, dim3(64 * SPLITK), dim3(256), 0, stream, x, w1, p);
  hipLaunchKernelGGL(k2_conv, dim3(512), dim3(256), 0, stream, p, b1, cw, cb, w2, b2, em);
  hipLaunchKernelGGL(k3_crf, dim3(NB), dim3(256), 0, stream, em, tl, lb, st, en, tr, llh, out);
  hipLaunchKernelGGL(k4_final, dim3(1), dim3(64), 0, stream, llh, out);
}